// Round 14
// baseline (273.146 us; speedup 1.0000x reference)
//
#include <hip/hip_runtime.h>
#include <math.h>

#define NND 50000
#define NED 800000
#define NGR 2048
#define NT  1024          // rad-table entries (uniform in xe = exp(-d))
#define NB  512           // bins of NPB nodes
#define NPB 98
#define HALF 49           // nodes per agg block (half-bin)
#define EPB 2048          // edges per bin block
#define BIN_BLOCKS 391    // ceil(NED / EPB)
#define TBL_BLOCKS 16     // 16 blocks x 64 entries = NT
#define LCAP 24           // per-(block,bin) capacity (Poisson(4); P(>24) ~ 1e-10)
#define LSTR 25           // LDS row stride
#define SCAP 1152         // sorted-geo LDS capacity per half-bin (mean 781, +13 sigma)
#define OFCAP 256         // global overflow capacity (expected usage: 0)

// exp(-5) and derived RBF constants, computed in double then rounded once.
constexpr double dSTART = 0.006737946999085467;
constexpr float  K_START = (float)dSTART;
constexpr float  K_STEP  = (float)((1.0 - dSTART) / 127.0);
constexpr float  K_BETA  = (float)(1.0 / ((2.0/128.0*(1.0-dSTART)) * (2.0/128.0*(1.0-dSTART))));
constexpr float  K_TSTEP = (float)((1.0 - dSTART) / (double)(NT - 1));
constexpr float  K_INVT  = (float)((double)(NT - 1) / (1.0 - dSTART));

__device__ __forceinline__ float silu_f(float x) {
    return x * __builtin_amdgcn_rcpf(1.0f + __expf(-x));
}

// ---------------- phase 1: atomic-free binning || rad-table build ----------------
// Bin blocks: block bid owns bins[bid][512][24] + cnts[bid][512] — LDS multisplit
// then a fully COALESCED dump (no global atomics, no scattered stores; round 13's
// 93us/0.8%VALU bottleneck was 100k device-atomics on a 2KB array + serial
// scattered flush). LDS overflow (P~2e-5 for this dataset) -> tiny global list.
// Table blocks: 16 x 1 wave tabulate rad(xe) in parallel; also zero out[].
__global__ void __launch_bounds__(1024)
bin_table(const int* __restrict__ esrc, const int* __restrict__ edst,
          unsigned* __restrict__ bins, int* __restrict__ cnts,
          int* __restrict__ of_cnt, int* __restrict__ of_src, int* __restrict__ of_dst,
          const float* __restrict__ W1, const float* __restrict__ b1,
          const float* __restrict__ W2, const float* __restrict__ b2,
          const float* __restrict__ W3, float* __restrict__ table,
          float* __restrict__ out)
{
    __shared__ unsigned smem[NB + NB * LSTR];    // 53.2 KB; table path aliases as float hb
    const int bid = blockIdx.x;
    const int tid = threadIdx.x;

    if (bid < BIN_BLOCKS) {
        int*      lcnt = (int*)smem;
        unsigned* lbuf = smem + NB;
        if (tid < NB) lcnt[tid] = 0;
        __syncthreads();
        const int e0 = bid * EPB;
        #pragma unroll
        for (int r = 0; r < 2; ++r) {
            int e = e0 + r * 1024 + tid;
            if (e < NED) {
                int dst = edst[e];
                int src = esrc[e];
                int b = dst / NPB;                       // const divide -> magic mul
                unsigned rec = ((unsigned)src << 7) | (unsigned)(dst - b * NPB);
                int p = atomicAdd(&lcnt[b], 1);          // LDS atomic, ~2 per bin
                if (p < LCAP) lbuf[b * LSTR + p] = rec;
                else {                                   // ~never fires
                    int gp = atomicAdd(of_cnt, 1);
                    if (gp < OFCAP) { of_src[gp] = src; of_dst[gp] = dst; }
                }
            }
        }
        __syncthreads();
        // coalesced dump of the whole LDS bin array (invalid slots guarded by cnts)
        unsigned* dp = bins + (size_t)bid * NB * LCAP;
        for (int i = tid; i < NB * LCAP; i += 1024) {
            int seg = i / LCAP, k = i - seg * LCAP;
            dp[i] = lbuf[seg * LSTR + k];
        }
        if (tid < NB) {
            int c = lcnt[tid];
            cnts[bid * NB + tid] = c < LCAP ? c : LCAP;
        }
        return;
    }

    // ---- table path: 16 blocks x 1 wave; also zero out[2048] ----
    const int tb = bid - BIN_BLOCKS;                    // 0..15
    if (tid < 128) out[tb * 128 + tid] = 0.0f;
    if (tid >= 64) return;
    const int ti = tb * 64 + tid;                       // 0..1023
    const int l  = tid;
    float* hb = (float*)smem;                           // [64][17]

    const float xe = K_START + K_TSTEP * (float)ti;
    const float dd = -logf(xe);
    const float cutv = (dd < 5.0f) ? (0.5f * (__cosf(dd * 0.6283185307179586f) + 1.0f)) : 0.0f;

    float h1[64];
    {
        const float4* bp = (const float4*)b1;
        #pragma unroll
        for (int j4 = 0; j4 < 16; ++j4) {
            float4 b = bp[j4];
            h1[4*j4+0] = b.x; h1[4*j4+1] = b.y; h1[4*j4+2] = b.z; h1[4*j4+3] = b.w;
        }
    }
    #pragma unroll 2
    for (int k = 0; k < 128; ++k) {
        float mean = K_START + K_STEP * (float)k;
        float t = xe - mean;
        float rk = cutv * __expf(-K_BETA * t * t);
        const float4* wr = (const float4*)(W1 + (k << 6));
        #pragma unroll
        for (int j4 = 0; j4 < 16; ++j4) {
            float4 wv = wr[j4];
            h1[4*j4+0] = fmaf(rk, wv.x, h1[4*j4+0]);
            h1[4*j4+1] = fmaf(rk, wv.y, h1[4*j4+1]);
            h1[4*j4+2] = fmaf(rk, wv.z, h1[4*j4+2]);
            h1[4*j4+3] = fmaf(rk, wv.w, h1[4*j4+3]);
        }
    }

    float h2[64];
    {
        const float4* bp = (const float4*)b2;
        #pragma unroll
        for (int j4 = 0; j4 < 16; ++j4) {
            float4 b = bp[j4];
            h2[4*j4+0] = b.x; h2[4*j4+1] = b.y; h2[4*j4+2] = b.z; h2[4*j4+3] = b.w;
        }
    }
    #pragma unroll
    for (int ch = 0; ch < 4; ++ch) {
        #pragma unroll
        for (int j = 0; j < 16; ++j) hb[l*17 + j] = silu_f(h1[ch*16 + j]);
        for (int k = 0; k < 16; ++k) {
            float hk = hb[l*17 + k];
            const float4* wr = (const float4*)(W2 + ((ch*16 + k) << 6));
            #pragma unroll
            for (int j4 = 0; j4 < 16; ++j4) {
                float4 wv = wr[j4];
                h2[4*j4+0] = fmaf(hk, wv.x, h2[4*j4+0]);
                h2[4*j4+1] = fmaf(hk, wv.y, h2[4*j4+1]);
                h2[4*j4+2] = fmaf(hk, wv.z, h2[4*j4+2]);
                h2[4*j4+3] = fmaf(hk, wv.w, h2[4*j4+3]);
            }
        }
    }

    float rad[16];
    #pragma unroll
    for (int cc = 0; cc < 16; ++cc) rad[cc] = 0.0f;
    #pragma unroll
    for (int ch = 0; ch < 4; ++ch) {
        #pragma unroll
        for (int j = 0; j < 16; ++j) hb[l*17 + j] = silu_f(h2[ch*16 + j]);
        for (int k = 0; k < 16; ++k) {
            float hk = hb[l*17 + k];
            const float4* wr = (const float4*)(W3 + ((ch*16 + k) << 4));
            #pragma unroll
            for (int c4 = 0; c4 < 4; ++c4) {
                float4 wv = wr[c4];
                rad[4*c4+0] = fmaf(hk, wv.x, rad[4*c4+0]);
                rad[4*c4+1] = fmaf(hk, wv.y, rad[4*c4+1]);
                rad[4*c4+2] = fmaf(hk, wv.z, rad[4*c4+2]);
                rad[4*c4+3] = fmaf(hk, wv.w, rad[4*c4+3]);
            }
        }
    }

    float4* rp = (float4*)(table + (size_t)ti * 16);
    rp[0] = make_float4(rad[0],  rad[1],  rad[2],  rad[3]);
    rp[1] = make_float4(rad[4],  rad[5],  rad[6],  rad[7]);
    rp[2] = make_float4(rad[8],  rad[9],  rad[10], rad[11]);
    rp[3] = make_float4(rad[12], rad[13], rad[14], rad[15]);
}

// ---------------- phase 2: slot-scan + counting sort + register agg + head ----------------
// One block per HALF-bin. Reads its bin's column: 391 segments x 24 slots,
// valid iff k < cnts[seg][b] (segment counts cached in LDS). Pass A counts,
// wave-scan, pass B computes geometry and scatters float4 into sorted LDS
// (dead edges -> (0,0,0,K_START) sentinel -> table[0]==0 -> exact zero).
// Aggregation: 8-lane group streams its node's sorted records (broadcast LDS
// reads, REGISTER accumulate). Head unchanged (proven 62% VALUBusy).
__global__ void __launch_bounds__(448)
agg_head(const float* __restrict__ pos,
         const unsigned* __restrict__ bins, const int* __restrict__ cnts,
         const int* __restrict__ of_cnt, const int* __restrict__ of_src,
         const int* __restrict__ of_dst,
         const float* __restrict__ table,
         const float* __restrict__ atom_table, const int* __restrict__ node_atom,
         const int* __restrict__ batch,
         const float* __restrict__ Wh1, const float* __restrict__ bh1,
         const float* __restrict__ Wh2, const float* __restrict__ bh2,
         float* __restrict__ out, float isd, float isn)
{
    __shared__ int    lcnt[HALF], soff[HALF], scur[HALF];
    __shared__ int    ccache[BIN_BLOCKS];          // 1.6 KB
    __shared__ float4 sgeo[SCAP];                  // 18.4 KB
    __shared__ float  nf_s[7][8][144];             // 32.3 KB
    const int tid = threadIdx.x;
    const int b   = blockIdx.x >> 1;
    const int h   = blockIdx.x & 1;
    const int lbase = h * HALF;
    const int gbase = b * NPB + lbase;

    if (tid < HALF) lcnt[tid] = 0;
    for (int i = tid; i < BIN_BLOCKS; i += 448) ccache[i] = cnts[i * NB + b];
    __syncthreads();

    int ofn = *of_cnt; ofn = ofn < OFCAP ? ofn : OFCAP;   // ~always 0

    // ---- pass A: count this half's records ----
    const int TOT = BIN_BLOCKS * LCAP;             // 9384 slots
    for (int s = tid; s < TOT; s += 448) {
        int seg = s / LCAP, k = s - seg * LCAP;
        if (k < ccache[seg]) {
            unsigned rec = bins[((size_t)seg * NB + b) * LCAP + k];
            int l = (int)(rec & 127u) - lbase;
            if (l >= 0 && l < HALF) atomicAdd(&lcnt[l], 1);
        }
    }
    for (int i = tid; i < ofn; i += 448) {
        int l = of_dst[i] - gbase;
        if (l >= 0 && l < HALF) atomicAdd(&lcnt[l], 1);
    }
    __syncthreads();

    // ---- exclusive scan over 49 counters (wave 0) ----
    if (tid < 64) {
        int v = (tid < HALF) ? lcnt[tid] : 0;
        int x = v;
        #pragma unroll
        for (int off = 1; off < 64; off <<= 1) {
            int u = __shfl_up(x, off);
            if (tid >= off) x += u;
        }
        if (tid < HALF) { soff[tid] = x - v; scur[tid] = x - v; }
    }
    __syncthreads();

    // ---- pass B: geometry + scatter into sorted LDS ----
    for (int s = tid; s < TOT; s += 448) {
        int seg = s / LCAP, k = s - seg * LCAP;
        if (k >= ccache[seg]) continue;
        unsigned rec = bins[((size_t)seg * NB + b) * LCAP + k];
        int local = (int)(rec & 127u);
        int l = local - lbase;
        if (l < 0 || l >= HALF) continue;
        int src = (int)(rec >> 7);
        int dst = b * NPB + local;
        float vx = pos[3*src+0] - pos[3*dst+0];
        float vy = pos[3*src+1] - pos[3*dst+1];
        float vz = pos[3*src+2] - pos[3*dst+2];
        float d2 = vx*vx + vy*vy + vz*vz;
        float4 g;
        if (d2 < 25.0f) {
            float ddv = sqrtf(d2);
            float inv = 1.0f / fmaxf(ddv, 1e-12f);
            g = make_float4(vx*inv, vy*inv, vz*inv, __expf(-ddv));
        } else {
            g = make_float4(0.0f, 0.0f, 0.0f, K_START);   // exact-zero sentinel
        }
        int p = atomicAdd(&scur[l], 1);
        if (p < SCAP) sgeo[p] = g;
    }
    for (int i = tid; i < ofn; i += 448) {
        int dst = of_dst[i];
        int l = dst - gbase;
        if (l < 0 || l >= HALF) continue;
        int src = of_src[i];
        float vx = pos[3*src+0] - pos[3*dst+0];
        float vy = pos[3*src+1] - pos[3*dst+1];
        float vz = pos[3*src+2] - pos[3*dst+2];
        float d2 = vx*vx + vy*vy + vz*vz;
        float4 g;
        if (d2 < 25.0f) {
            float ddv = sqrtf(d2);
            float inv = 1.0f / fmaxf(ddv, 1e-12f);
            g = make_float4(vx*inv, vy*inv, vz*inv, __expf(-ddv));
        } else {
            g = make_float4(0.0f, 0.0f, 0.0f, K_START);
        }
        int p = atomicAdd(&scur[l], 1);
        if (p < SCAP) sgeo[p] = g;
    }
    __syncthreads();

    // ---- aggregation: wave w, group g -> node slot l = w*8+g ----
    const int lane = tid & 63;
    const int w    = tid >> 6;           // 0..6
    const int g    = lane >> 3;
    const int c    = lane & 7;           // channels c and c+8
    const int l    = w * 8 + g;          // valid < HALF
    const int gn   = gbase + l;
    const bool valid = (l < HALF) && (gn < NND);

    float acc0[9], acc1[9];
    #pragma unroll
    for (int s = 0; s < 9; ++s) { acc0[s] = 0.0f; acc1[s] = 0.0f; }

    int start = 0, end = 0;
    if (valid) {
        start = soff[l];
        end   = start + lcnt[l];
        end   = end < SCAP ? end : SCAP;
    }

    for (int p = start; p < end; ++p) {
        float4 gv = sgeo[p];             // all 8 group lanes same addr -> broadcast
        float ux = gv.x, uy = gv.y, uz = gv.z, xe = gv.w;

        float t = (xe - K_START) * K_INVT;
        int i0 = (int)t;
        i0 = i0 < 0 ? 0 : (i0 > NT-2 ? NT-2 : i0);
        float fr = t - (float)i0;
        const float* tb = table + (size_t)i0 * 16 + c;
        float r0a = tb[0], r1a = tb[16];
        float r0b = tb[8], r1b = tb[24];
        float ra = fmaf(fr, r1a - r0a, r0a);
        float rb = fmaf(fr, r1b - r0b, r0b);

        float sh1 = 1.7320508075688772f * ux;
        float sh2 = 1.7320508075688772f * uy;
        float sh3 = 1.7320508075688772f * uz;
        float sh4 = 3.872983346207417f * ux * uz;
        float sh5 = 3.872983346207417f * ux * uy;
        float sh6 = 2.23606797749979f * (uy*uy - 0.5f*(ux*ux + uz*uz));
        float sh7 = 3.872983346207417f * uy * uz;
        float sh8 = 1.9364916731037085f * (uz*uz - ux*ux);

        acc0[0] += ra;                    acc1[0] += rb;
        acc0[1] = fmaf(ra, sh1, acc0[1]); acc1[1] = fmaf(rb, sh1, acc1[1]);
        acc0[2] = fmaf(ra, sh2, acc0[2]); acc1[2] = fmaf(rb, sh2, acc1[2]);
        acc0[3] = fmaf(ra, sh3, acc0[3]); acc1[3] = fmaf(rb, sh3, acc1[3]);
        acc0[4] = fmaf(ra, sh4, acc0[4]); acc1[4] = fmaf(rb, sh4, acc1[4]);
        acc0[5] = fmaf(ra, sh5, acc0[5]); acc1[5] = fmaf(rb, sh5, acc1[5]);
        acc0[6] = fmaf(ra, sh6, acc0[6]); acc1[6] = fmaf(rb, sh6, acc1[6]);
        acc0[7] = fmaf(ra, sh7, acc0[7]); acc1[7] = fmaf(rb, sh7, acc1[7]);
        acc0[8] = fmaf(ra, sh8, acc0[8]); acc1[8] = fmaf(rb, sh8, acc1[8]);
    }

    // nf = atom_table[atom] + deg_embed * isd -> this wave's LDS slab
    {
        int a = valid ? node_atom[gn] : 0;
        const float* at = atom_table + (size_t)a * 144;
        #pragma unroll
        for (int s = 0; s < 9; ++s) {
            nf_s[w][g][c*9 + s]     = fmaf(acc0[s], isd, at[c*9 + s]);
            nf_s[w][g][(c+8)*9 + s] = fmaf(acc1[s], isd, at[(c+8)*9 + s]);
        }
    }
    // same-wave LDS write->read: hardware-ordered, no barrier

    // ---- head: hn = silu(nf @ Wh1 + bh1); energy = hn @ Wh2 + bh2 ----
    float A0[8], A1[8], A2[8];
    {
        float bb0 = bh1[lane], bb1 = bh1[lane + 64];
        float bb2 = (lane < 16) ? bh1[lane + 128] : 0.0f;
        #pragma unroll
        for (int q = 0; q < 8; ++q) { A0[q] = bb0; A1[q] = bb1; A2[q] = bb2; }
    }

    for (int k4 = 0; k4 < 36; ++k4) {
        float4 nq[8];
        #pragma unroll
        for (int q = 0; q < 8; ++q)
            nq[q] = *(const float4*)&nf_s[w][q][k4*4];      // LDS broadcast
        const float* wrow = Wh1 + (size_t)(k4*4) * 144;     // L2-hot global
#define HSTEP(COMP, OFF) { \
        float w0 = wrow[(OFF)*144 + lane]; \
        float w1 = wrow[(OFF)*144 + lane + 64]; \
        float w2 = (lane < 16) ? wrow[(OFF)*144 + lane + 128] : 0.0f; \
        _Pragma("unroll") \
        for (int q = 0; q < 8; ++q) { \
            float nk = nq[q].COMP; \
            A0[q] = fmaf(nk, w0, A0[q]); \
            A1[q] = fmaf(nk, w1, A1[q]); \
            A2[q] = fmaf(nk, w2, A2[q]); } }
        HSTEP(x, 0) HSTEP(y, 1) HSTEP(z, 2) HSTEP(w, 3)
#undef HSTEP
    }

    float wl0 = Wh2[lane], wl1 = Wh2[lane + 64];
    float wl2 = (lane < 16) ? Wh2[lane + 128] : 0.0f;
    float bv  = bh2[0];
    #pragma unroll
    for (int q = 0; q < 8; ++q) {
        float en = silu_f(A0[q]) * wl0 + silu_f(A1[q]) * wl1;
        if (lane < 16) en = fmaf(silu_f(A2[q]), wl2, en);
        en += __shfl_down(en, 32);
        en += __shfl_down(en, 16);
        en += __shfl_down(en, 8);
        en += __shfl_down(en, 4);
        en += __shfl_down(en, 2);
        en += __shfl_down(en, 1);
        int lq = w * 8 + q;
        int gq = gbase + lq;
        if (lane == 0 && lq < HALF && gq < NND) {
            unsafeAtomicAdd(out + batch[gq], (en + bv) * isn);
        }
    }
}

extern "C" void kernel_launch(void* const* d_in, const int* in_sizes, int n_in,
                              void* d_out, int out_size, void* d_ws, size_t ws_size,
                              hipStream_t stream) {
    const float* pos        = (const float*)d_in[0];
    const float* atom_table = (const float*)d_in[1];
    const float* W1         = (const float*)d_in[2];
    const float* b1         = (const float*)d_in[3];
    const float* W2         = (const float*)d_in[4];
    const float* b2         = (const float*)d_in[5];
    const float* W3         = (const float*)d_in[6];
    const float* Wh1        = (const float*)d_in[7];
    const float* bh1        = (const float*)d_in[8];
    const float* Wh2        = (const float*)d_in[9];
    const float* bh2        = (const float*)d_in[10];
    const int*   node_atom  = (const int*)d_in[11];
    const int*   edge_src   = (const int*)d_in[12];
    const int*   edge_dst   = (const int*)d_in[13];
    const int*   batch      = (const int*)d_in[14];

    float* out = (float*)d_out;

    // workspace layout (16B-aligned where needed)
    char*     wsb    = (char*)d_ws;
    int*      of_cnt = (int*)(wsb);                  // [1] + pad       64 B
    int*      of_src = (int*)(wsb + 64);             // [OFCAP]         1024 B
    int*      of_dst = (int*)(wsb + 1088);           // [OFCAP]         1024 B
    float*    table  = (float*)(wsb + 2112);         // [NT][16]        65536 B (16B-al)
    int*      cnts   = (int*)(wsb + 67648);          // [391][512]      800768 B
    unsigned* bins   = (unsigned*)(wsb + 868416);    // [391][512][24]  19.2 MB (16B-al)

    hipMemsetAsync(of_cnt, 0, 4, stream);

    bin_table<<<BIN_BLOCKS + TBL_BLOCKS, 1024, 0, stream>>>(
        edge_src, edge_dst, bins, cnts, of_cnt, of_src, of_dst,
        W1, b1, W2, b2, W3, table, out);

    float isd = 1.0f / sqrtf(15.57930850982666f);
    float isn = 1.0f / sqrtf(18.03065905448718f);
    agg_head<<<NB * 2, 448, 0, stream>>>(
        pos, bins, cnts, of_cnt, of_src, of_dst, table, atom_table, node_atom,
        batch, Wh1, bh1, Wh2, bh2, out, isd, isn);
}

// Round 15
// 250.611 us; speedup vs baseline: 1.0899x; 1.0899x over previous
//
#include <hip/hip_runtime.h>
#include <math.h>

#define NND 50000
#define NED 800000
#define NGR 2048
#define NT  1024          // rad-table entries (uniform in xe = exp(-d))
#define NB  512           // bins of NPB nodes
#define NPB 98
#define EPB 8192          // edges per bin block
#define BIN_BLOCKS 98     // ceil(NED / EPB) = 98 (98*8192 = 802816)
#define CHW 32            // chunk words: [count, 31 records] = 128 B = 2 lines
#define LCAP 31           // records per chunk (lambda=16; P(>31) ~ 2e-4/chunk)
#define SCAP 2048         // sorted-geo LDS capacity per bin (mean 1562, +12 sigma)
#define OFCAP 4096        // global overflow capacity (expected usage ~15)
#define AGG_T 832         // 13 waves; 13*8 = 104 node slots >= 98

// exp(-5) and derived RBF constants, computed in double then rounded once.
constexpr double dSTART = 0.006737946999085467;
constexpr float  K_START = (float)dSTART;
constexpr float  K_STEP  = (float)((1.0 - dSTART) / 127.0);
constexpr float  K_BETA  = (float)(1.0 / ((2.0/128.0*(1.0-dSTART)) * (2.0/128.0*(1.0-dSTART))));
constexpr float  K_TSTEP = (float)((1.0 - dSTART) / (double)(NT - 1));
constexpr float  K_INVT  = (float)((double)(NT - 1) / (1.0 - dSTART));

__device__ __forceinline__ float silu_f(float x) {
    return x * __builtin_amdgcn_rcpf(1.0f + __expf(-x));
}

// ---------------- phase 1: LDS-multisplit binning, chunk layout ----------------
// Block seg owns 8192 edges. LDS [512][32]: word 0 = count (LDS atomic), words
// 1..31 = records. Dump is bin-major: bins[b][seg][32] -> full-2-line coalesced
// writes (no global atomics), AND agg block b later reads bins[b][*][*] as one
// CONTIGUOUS 12.5 KB region (round 14's column layout cost 48 MB of strided
// fetch; round 13's flush cost 100k device atomics — this has neither).
__global__ void __launch_bounds__(1024)
bin_kernel(const int* __restrict__ esrc, const int* __restrict__ edst,
           unsigned* __restrict__ bins,
           int* __restrict__ of_cnt, int* __restrict__ of_src, int* __restrict__ of_dst)
{
    __shared__ unsigned lbuf[NB * CHW];          // 64 KB
    const int seg = blockIdx.x;
    const int tid = threadIdx.x;

    if (tid < NB) lbuf[tid * CHW] = 0;           // zero count words
    __syncthreads();

    const int e0 = seg * EPB;
    #pragma unroll
    for (int r = 0; r < 8; ++r) {
        int e = e0 + r * 1024 + tid;
        if (e < NED) {
            int dst = edst[e];
            int src = esrc[e];
            int b = dst / NPB;                   // const divide -> magic mul
            unsigned rec = ((unsigned)src << 7) | (unsigned)(dst - b * NPB);
            int p = atomicAdd((int*)&lbuf[b * CHW], 1);
            if (p < LCAP) lbuf[b * CHW + 1 + p] = rec;
            else {                               // rare (~15 edges total)
                int gp = atomicAdd(of_cnt, 1);
                if (gp < OFCAP) { of_src[gp] = src; of_dst[gp] = dst; }
            }
        }
    }
    __syncthreads();
    // coalesced dump: 32 consecutive threads write one 128 B chunk (2 full lines)
    for (int i = tid; i < NB * CHW; i += 1024) {
        int b = i >> 5, k = i & 31;
        bins[((size_t)b * BIN_BLOCKS + seg) * CHW + k] = lbuf[i];
    }
}

// ---------------- phase 2: rad-table build (round-5 proven shape) ----------------
// 16 blocks x 64 threads; blocks also zero out[2048] (2 elems/thread).
__global__ void __launch_bounds__(64)
table_kernel(const float* __restrict__ W1, const float* __restrict__ b1,
             const float* __restrict__ W2, const float* __restrict__ b2,
             const float* __restrict__ W3, float* __restrict__ table,
             float* __restrict__ out)
{
    __shared__ float hb[64][17];
    const int lane = threadIdx.x;
    const int ti   = blockIdx.x * 64 + lane;     // 0..1023

    out[(blockIdx.x * 64 + lane) * 2 + 0] = 0.0f;
    out[(blockIdx.x * 64 + lane) * 2 + 1] = 0.0f;

    const float xe = K_START + K_TSTEP * (float)ti;
    const float dd = -logf(xe);
    const float cutv = (dd < 5.0f) ? (0.5f * (__cosf(dd * 0.6283185307179586f) + 1.0f)) : 0.0f;

    float h1[64];
    {
        const float4* bp = (const float4*)b1;
        #pragma unroll
        for (int j4 = 0; j4 < 16; ++j4) {
            float4 b = bp[j4];
            h1[4*j4+0] = b.x; h1[4*j4+1] = b.y; h1[4*j4+2] = b.z; h1[4*j4+3] = b.w;
        }
    }
    #pragma unroll 2
    for (int k = 0; k < 128; ++k) {
        float mean = K_START + K_STEP * (float)k;
        float t = xe - mean;
        float rk = cutv * __expf(-K_BETA * t * t);
        const float4* wr = (const float4*)(W1 + (k << 6));
        #pragma unroll
        for (int j4 = 0; j4 < 16; ++j4) {
            float4 wv = wr[j4];
            h1[4*j4+0] = fmaf(rk, wv.x, h1[4*j4+0]);
            h1[4*j4+1] = fmaf(rk, wv.y, h1[4*j4+1]);
            h1[4*j4+2] = fmaf(rk, wv.z, h1[4*j4+2]);
            h1[4*j4+3] = fmaf(rk, wv.w, h1[4*j4+3]);
        }
    }

    float h2[64];
    {
        const float4* bp = (const float4*)b2;
        #pragma unroll
        for (int j4 = 0; j4 < 16; ++j4) {
            float4 b = bp[j4];
            h2[4*j4+0] = b.x; h2[4*j4+1] = b.y; h2[4*j4+2] = b.z; h2[4*j4+3] = b.w;
        }
    }
    #pragma unroll
    for (int ch = 0; ch < 4; ++ch) {
        #pragma unroll
        for (int j = 0; j < 16; ++j) hb[lane][j] = silu_f(h1[ch*16 + j]);
        for (int k = 0; k < 16; ++k) {
            float hk = hb[lane][k];
            const float4* wr = (const float4*)(W2 + ((ch*16 + k) << 6));
            #pragma unroll
            for (int j4 = 0; j4 < 16; ++j4) {
                float4 wv = wr[j4];
                h2[4*j4+0] = fmaf(hk, wv.x, h2[4*j4+0]);
                h2[4*j4+1] = fmaf(hk, wv.y, h2[4*j4+1]);
                h2[4*j4+2] = fmaf(hk, wv.z, h2[4*j4+2]);
                h2[4*j4+3] = fmaf(hk, wv.w, h2[4*j4+3]);
            }
        }
    }

    float rad[16];
    #pragma unroll
    for (int cc = 0; cc < 16; ++cc) rad[cc] = 0.0f;
    #pragma unroll
    for (int ch = 0; ch < 4; ++ch) {
        #pragma unroll
        for (int j = 0; j < 16; ++j) hb[lane][j] = silu_f(h2[ch*16 + j]);
        for (int k = 0; k < 16; ++k) {
            float hk = hb[lane][k];
            const float4* wr = (const float4*)(W3 + ((ch*16 + k) << 4));
            #pragma unroll
            for (int c4 = 0; c4 < 4; ++c4) {
                float4 wv = wr[c4];
                rad[4*c4+0] = fmaf(hk, wv.x, rad[4*c4+0]);
                rad[4*c4+1] = fmaf(hk, wv.y, rad[4*c4+1]);
                rad[4*c4+2] = fmaf(hk, wv.z, rad[4*c4+2]);
                rad[4*c4+3] = fmaf(hk, wv.w, rad[4*c4+3]);
            }
        }
    }

    float4* rp = (float4*)(table + (size_t)ti * 16);
    rp[0] = make_float4(rad[0],  rad[1],  rad[2],  rad[3]);
    rp[1] = make_float4(rad[4],  rad[5],  rad[6],  rad[7]);
    rp[2] = make_float4(rad[8],  rad[9],  rad[10], rad[11]);
    rp[3] = make_float4(rad[12], rad[13], rad[14], rad[15]);
}

// ---------------- phase 3: full-bin counting sort + register agg + head ----------------
// One block per bin (98 nodes, 13 waves). The bin's chunk region is 12.5 KB
// CONTIGUOUS (fits L1 -> pass B is L1-hot; total HBM fetch ~6.4 MB like round
// 13, not round 14's 48 MB). Pass A counts per node, two-step wave scan,
// pass B computes geometry (dead edges -> (0,0,0,K_START) sentinel ->
// table[0]==0 -> exact zero) and scatters float4 into sorted LDS. Aggregation:
// 8-lane group streams its node's records (broadcast LDS reads, REGISTER
// accumulate — round 13's proven 62% VALUBusy structure). Head unchanged.
__global__ void __launch_bounds__(AGG_T)
agg_head(const float* __restrict__ pos, const unsigned* __restrict__ bins,
         const int* __restrict__ of_cnt, const int* __restrict__ of_src,
         const int* __restrict__ of_dst,
         const float* __restrict__ table,
         const float* __restrict__ atom_table, const int* __restrict__ node_atom,
         const int* __restrict__ batch,
         const float* __restrict__ Wh1, const float* __restrict__ bh1,
         const float* __restrict__ Wh2, const float* __restrict__ bh2,
         float* __restrict__ out, float isd, float isn)
{
    __shared__ int    lcnt[104], soff[104], scur[104];
    __shared__ int    ccache[BIN_BLOCKS];
    __shared__ float4 sgeo[SCAP];                  // 32 KB
    __shared__ float  nf_s[13][8][144];            // 59.9 KB
    const int tid = threadIdx.x;
    const int b   = blockIdx.x;
    const int gbase = b * NPB;
    const unsigned* myreg = bins + (size_t)b * BIN_BLOCKS * CHW;   // 12.5 KB contiguous

    if (tid < 104) lcnt[tid] = 0;
    if (tid < BIN_BLOCKS) {
        int c = (int)myreg[tid * CHW];
        ccache[tid] = c < LCAP ? c : LCAP;
    }
    __syncthreads();

    int ofn = *of_cnt; ofn = ofn < OFCAP ? ofn : OFCAP;   // ~15

    // ---- pass A: count records per node ----
    const int TOT = BIN_BLOCKS * CHW;              // 3136 words
    for (int s = tid; s < TOT; s += AGG_T) {
        int seg = s >> 5, k = s & 31;
        if (k >= 1 && k <= ccache[seg]) {
            int l = (int)(myreg[s] & 127u);
            atomicAdd(&lcnt[l], 1);
        }
    }
    for (int i = tid; i < ofn; i += AGG_T) {
        int l = of_dst[i] - gbase;
        if (l >= 0 && l < NPB) atomicAdd(&lcnt[l], 1);
    }
    __syncthreads();

    // ---- exclusive scan over 98 counters (wave 0, two steps) ----
    if (tid < 64) {
        int v = lcnt[tid];
        int x = v;
        #pragma unroll
        for (int off = 1; off < 64; off <<= 1) {
            int u = __shfl_up(x, off);
            if (tid >= off) x += u;
        }
        soff[tid] = x - v; scur[tid] = x - v;
        int tot64 = __shfl(x, 63);
        int v2 = (tid < 40) ? lcnt[64 + tid] : 0;  // 64+34=98; pad to 40
        int x2 = v2;
        #pragma unroll
        for (int off = 1; off < 64; off <<= 1) {
            int u = __shfl_up(x2, off);
            if (tid >= off) x2 += u;
        }
        if (tid < 40) { soff[64 + tid] = tot64 + x2 - v2; scur[64 + tid] = tot64 + x2 - v2; }
    }
    __syncthreads();

    // ---- pass B: geometry + scatter into sorted LDS (region is L1-hot) ----
    for (int s = tid; s < TOT; s += AGG_T) {
        int seg = s >> 5, k = s & 31;
        if (k < 1 || k > ccache[seg]) continue;
        unsigned rec = myreg[s];
        int local = (int)(rec & 127u);
        int src = (int)(rec >> 7);
        int dst = gbase + local;
        float vx = pos[3*src+0] - pos[3*dst+0];
        float vy = pos[3*src+1] - pos[3*dst+1];
        float vz = pos[3*src+2] - pos[3*dst+2];
        float d2 = vx*vx + vy*vy + vz*vz;
        float4 g;
        if (d2 < 25.0f) {
            float ddv = sqrtf(d2);
            float inv = 1.0f / fmaxf(ddv, 1e-12f);
            g = make_float4(vx*inv, vy*inv, vz*inv, __expf(-ddv));
        } else {
            g = make_float4(0.0f, 0.0f, 0.0f, K_START);   // exact-zero sentinel
        }
        int p = atomicAdd(&scur[local], 1);
        if (p < SCAP) sgeo[p] = g;
    }
    for (int i = tid; i < ofn; i += AGG_T) {
        int dst = of_dst[i];
        int l = dst - gbase;
        if (l < 0 || l >= NPB) continue;
        int src = of_src[i];
        float vx = pos[3*src+0] - pos[3*dst+0];
        float vy = pos[3*src+1] - pos[3*dst+1];
        float vz = pos[3*src+2] - pos[3*dst+2];
        float d2 = vx*vx + vy*vy + vz*vz;
        float4 g;
        if (d2 < 25.0f) {
            float ddv = sqrtf(d2);
            float inv = 1.0f / fmaxf(ddv, 1e-12f);
            g = make_float4(vx*inv, vy*inv, vz*inv, __expf(-ddv));
        } else {
            g = make_float4(0.0f, 0.0f, 0.0f, K_START);
        }
        int p = atomicAdd(&scur[l], 1);
        if (p < SCAP) sgeo[p] = g;
    }
    __syncthreads();

    // ---- aggregation: wave w, group g -> node slot l = w*8+g ----
    const int lane = tid & 63;
    const int w    = tid >> 6;           // 0..12
    const int g    = lane >> 3;
    const int c    = lane & 7;           // channels c and c+8
    const int l    = w * 8 + g;          // valid < NPB
    const int gn   = gbase + l;
    const bool valid = (l < NPB) && (gn < NND);

    float acc0[9], acc1[9];
    #pragma unroll
    for (int s = 0; s < 9; ++s) { acc0[s] = 0.0f; acc1[s] = 0.0f; }

    int start = 0, end = 0;
    if (valid) {
        start = soff[l];
        end   = start + lcnt[l];
        end   = end < SCAP ? end : SCAP;
    }

    for (int p = start; p < end; ++p) {
        float4 gv = sgeo[p];             // all 8 group lanes same addr -> broadcast
        float ux = gv.x, uy = gv.y, uz = gv.z, xe = gv.w;

        float t = (xe - K_START) * K_INVT;
        int i0 = (int)t;
        i0 = i0 < 0 ? 0 : (i0 > NT-2 ? NT-2 : i0);
        float fr = t - (float)i0;
        const float* tb = table + (size_t)i0 * 16 + c;
        float r0a = tb[0], r1a = tb[16];
        float r0b = tb[8], r1b = tb[24];
        float ra = fmaf(fr, r1a - r0a, r0a);
        float rb = fmaf(fr, r1b - r0b, r0b);

        float sh1 = 1.7320508075688772f * ux;
        float sh2 = 1.7320508075688772f * uy;
        float sh3 = 1.7320508075688772f * uz;
        float sh4 = 3.872983346207417f * ux * uz;
        float sh5 = 3.872983346207417f * ux * uy;
        float sh6 = 2.23606797749979f * (uy*uy - 0.5f*(ux*ux + uz*uz));
        float sh7 = 3.872983346207417f * uy * uz;
        float sh8 = 1.9364916731037085f * (uz*uz - ux*ux);

        acc0[0] += ra;                    acc1[0] += rb;
        acc0[1] = fmaf(ra, sh1, acc0[1]); acc1[1] = fmaf(rb, sh1, acc1[1]);
        acc0[2] = fmaf(ra, sh2, acc0[2]); acc1[2] = fmaf(rb, sh2, acc1[2]);
        acc0[3] = fmaf(ra, sh3, acc0[3]); acc1[3] = fmaf(rb, sh3, acc1[3]);
        acc0[4] = fmaf(ra, sh4, acc0[4]); acc1[4] = fmaf(rb, sh4, acc1[4]);
        acc0[5] = fmaf(ra, sh5, acc0[5]); acc1[5] = fmaf(rb, sh5, acc1[5]);
        acc0[6] = fmaf(ra, sh6, acc0[6]); acc1[6] = fmaf(rb, sh6, acc1[6]);
        acc0[7] = fmaf(ra, sh7, acc0[7]); acc1[7] = fmaf(rb, sh7, acc1[7]);
        acc0[8] = fmaf(ra, sh8, acc0[8]); acc1[8] = fmaf(rb, sh8, acc1[8]);
    }

    // nf = atom_table[atom] + deg_embed * isd -> this wave's LDS slab
    {
        int a = valid ? node_atom[gn] : 0;
        const float* at = atom_table + (size_t)a * 144;
        #pragma unroll
        for (int s = 0; s < 9; ++s) {
            nf_s[w][g][c*9 + s]     = fmaf(acc0[s], isd, at[c*9 + s]);
            nf_s[w][g][(c+8)*9 + s] = fmaf(acc1[s], isd, at[(c+8)*9 + s]);
        }
    }
    // same-wave LDS write->read: hardware-ordered, no barrier

    // ---- head: hn = silu(nf @ Wh1 + bh1); energy = hn @ Wh2 + bh2 ----
    float A0[8], A1[8], A2[8];
    {
        float bb0 = bh1[lane], bb1 = bh1[lane + 64];
        float bb2 = (lane < 16) ? bh1[lane + 128] : 0.0f;
        #pragma unroll
        for (int q = 0; q < 8; ++q) { A0[q] = bb0; A1[q] = bb1; A2[q] = bb2; }
    }

    for (int k4 = 0; k4 < 36; ++k4) {
        float4 nq[8];
        #pragma unroll
        for (int q = 0; q < 8; ++q)
            nq[q] = *(const float4*)&nf_s[w][q][k4*4];      // LDS broadcast
        const float* wrow = Wh1 + (size_t)(k4*4) * 144;     // L2-hot global
#define HSTEP(COMP, OFF) { \
        float w0 = wrow[(OFF)*144 + lane]; \
        float w1 = wrow[(OFF)*144 + lane + 64]; \
        float w2 = (lane < 16) ? wrow[(OFF)*144 + lane + 128] : 0.0f; \
        _Pragma("unroll") \
        for (int q = 0; q < 8; ++q) { \
            float nk = nq[q].COMP; \
            A0[q] = fmaf(nk, w0, A0[q]); \
            A1[q] = fmaf(nk, w1, A1[q]); \
            A2[q] = fmaf(nk, w2, A2[q]); } }
        HSTEP(x, 0) HSTEP(y, 1) HSTEP(z, 2) HSTEP(w, 3)
#undef HSTEP
    }

    float wl0 = Wh2[lane], wl1 = Wh2[lane + 64];
    float wl2 = (lane < 16) ? Wh2[lane + 128] : 0.0f;
    float bv  = bh2[0];
    #pragma unroll
    for (int q = 0; q < 8; ++q) {
        float en = silu_f(A0[q]) * wl0 + silu_f(A1[q]) * wl1;
        if (lane < 16) en = fmaf(silu_f(A2[q]), wl2, en);
        en += __shfl_down(en, 32);
        en += __shfl_down(en, 16);
        en += __shfl_down(en, 8);
        en += __shfl_down(en, 4);
        en += __shfl_down(en, 2);
        en += __shfl_down(en, 1);
        int lq = w * 8 + q;
        int gq = gbase + lq;
        if (lane == 0 && lq < NPB && gq < NND) {
            unsafeAtomicAdd(out + batch[gq], (en + bv) * isn);
        }
    }
}

extern "C" void kernel_launch(void* const* d_in, const int* in_sizes, int n_in,
                              void* d_out, int out_size, void* d_ws, size_t ws_size,
                              hipStream_t stream) {
    const float* pos        = (const float*)d_in[0];
    const float* atom_table = (const float*)d_in[1];
    const float* W1         = (const float*)d_in[2];
    const float* b1         = (const float*)d_in[3];
    const float* W2         = (const float*)d_in[4];
    const float* b2         = (const float*)d_in[5];
    const float* W3         = (const float*)d_in[6];
    const float* Wh1        = (const float*)d_in[7];
    const float* bh1        = (const float*)d_in[8];
    const float* Wh2        = (const float*)d_in[9];
    const float* bh2        = (const float*)d_in[10];
    const int*   node_atom  = (const int*)d_in[11];
    const int*   edge_src   = (const int*)d_in[12];
    const int*   edge_dst   = (const int*)d_in[13];
    const int*   batch      = (const int*)d_in[14];

    float* out = (float*)d_out;

    // workspace layout (16B-aligned where needed)
    char*     wsb    = (char*)d_ws;
    int*      of_cnt = (int*)(wsb);                  // [1] + pad        64 B
    int*      of_src = (int*)(wsb + 64);             // [OFCAP]          16384 B
    int*      of_dst = (int*)(wsb + 16448);          // [OFCAP]          16384 B
    float*    table  = (float*)(wsb + 32832);        // [NT][16]         65536 B (16B-al)
    unsigned* bins   = (unsigned*)(wsb + 98368);     // [NB][98][32]     6.42 MB (16B-al)

    hipMemsetAsync(of_cnt, 0, 4, stream);

    bin_kernel<<<BIN_BLOCKS, 1024, 0, stream>>>(
        edge_src, edge_dst, bins, of_cnt, of_src, of_dst);

    table_kernel<<<NT / 64, 64, 0, stream>>>(W1, b1, W2, b2, W3, table, out);

    float isd = 1.0f / sqrtf(15.57930850982666f);
    float isn = 1.0f / sqrtf(18.03065905448718f);
    agg_head<<<NB, AGG_T, 0, stream>>>(
        pos, bins, of_cnt, of_src, of_dst, table, atom_table, node_atom,
        batch, Wh1, bh1, Wh2, bh2, out, isd, isn);
}

// Round 16
// 242.314 us; speedup vs baseline: 1.1272x; 1.0342x over previous
//
#include <hip/hip_runtime.h>
#include <math.h>

#define NND 50000
#define NED 800000
#define NGR 2048
#define NT  1024          // rad-table entries (uniform in xe = exp(-d))
#define NB  512           // bins of NPB nodes
#define NPB 98
#define HALF 49           // nodes per agg block (half-bin, round-13 proven shape)
#define EPB 4096          // edges per bin block
#define BIN_BLOCKS 196    // 196*4096 = 802816 >= NED
#define TBL_BLOCKS 16
#define CHW 16            // chunk = 16 words = exactly one 64 B line
#define LCAP 16           // slots 0..15; count packed in bits 27..31 of slot 0
#define LSTR 17           // LDS record row stride (odd -> banks spread)
#define SCAP 1152         // sorted-geo LDS capacity per half-bin (mean 784, +13 sigma)
#define OFCAP 8192        // global overflow capacity (expected usage ~300)
#define RECMASK 0x07FFFFFFu

// exp(-5) and derived RBF constants, computed in double then rounded once.
constexpr double dSTART = 0.006737946999085467;
constexpr float  K_START = (float)dSTART;
constexpr float  K_STEP  = (float)((1.0 - dSTART) / 127.0);
constexpr float  K_BETA  = (float)(1.0 / ((2.0/128.0*(1.0-dSTART)) * (2.0/128.0*(1.0-dSTART))));
constexpr float  K_TSTEP = (float)((1.0 - dSTART) / (double)(NT - 1));
constexpr float  K_INVT  = (float)((double)(NT - 1) / (1.0 - dSTART));

__device__ __forceinline__ float silu_f(float x) {
    return x * __builtin_amdgcn_rcpf(1.0f + __expf(-x));
}

// ---------------- phase 1: LDS-multisplit binning || rad-table build ----------------
// Bin blocks: dense lcnt[512] (counters spread over all 32 banks — round 15 put
// them ALL in bank 0 via the stride-32 layout: 800k serialized same-bank RMWs)
// + lbuf[512][17] records. NO global atomics (round 13's flush did 100k
// cross-XCD atomicAdds). Dump: bins[seg][b][16] — block streams its own
// contiguous 32 KB; chunk = one full 64 B line with count in bits 27..31 of
// slot 0. Overflow (P(Poisson(8)>16)~2e-3/chunk, ~300 total) -> global list.
// Table blocks: proven 1-wave MLP shape; also zero out[].
__global__ void __launch_bounds__(1024)
bin_table(const int* __restrict__ esrc, const int* __restrict__ edst,
          unsigned* __restrict__ bins,
          int* __restrict__ of_cnt, int* __restrict__ of_src, int* __restrict__ of_dst,
          const float* __restrict__ W1, const float* __restrict__ b1,
          const float* __restrict__ W2, const float* __restrict__ b2,
          const float* __restrict__ W3, float* __restrict__ table,
          float* __restrict__ out)
{
    __shared__ int      lcnt[NB];                // dense: bank = b%32
    __shared__ unsigned lbuf[NB * LSTR];         // 34.8 KB, odd stride
    const int bid = blockIdx.x;
    const int tid = threadIdx.x;

    if (bid < BIN_BLOCKS) {
        if (tid < NB) lcnt[tid] = 0;
        __syncthreads();
        const int e0 = bid * EPB;
        #pragma unroll
        for (int r = 0; r < 4; ++r) {
            int e = e0 + r * 1024 + tid;
            if (e < NED) {
                int dst = edst[e];
                int src = esrc[e];
                int b = dst / NPB;                   // const divide -> magic mul
                unsigned rec = ((unsigned)src << 7) | (unsigned)(dst - b * NPB);
                int p = atomicAdd(&lcnt[b], 1);
                if (p < LCAP) lbuf[b * LSTR + p] = rec;
                else {                               // ~300 edges total
                    int gp = atomicAdd(of_cnt, 1);
                    if (gp < OFCAP) { of_src[gp] = src; of_dst[gp] = dst; }
                }
            }
        }
        __syncthreads();
        // contiguous dump: this block owns bins[bid][*][*] = 32 KB stream
        unsigned* dp = bins + (size_t)bid * NB * CHW;
        for (int i = tid; i < NB * CHW; i += 1024) {
            int b = i >> 4, k = i & 15;
            int c = lcnt[b]; c = c < LCAP ? c : LCAP;
            unsigned val;
            if (k == 0) val = ((c > 0) ? lbuf[b * LSTR] : 0u) | ((unsigned)c << 27);
            else        val = lbuf[b * LSTR + k];    // garbage beyond c: reader-guarded
            dp[i] = val;
        }
        return;
    }

    // ---- table path: blocks 196..211, 1 wave active; also zero out[2048] ----
    const int tb = bid - BIN_BLOCKS;                 // 0..15
    if (tid < 128) out[tb * 128 + tid] = 0.0f;
    if (tid >= 64) return;
    const int ti = tb * 64 + tid;                    // 0..1023
    float* hb = (float*)lbuf;                        // alias [64][17]

    const float xe = K_START + K_TSTEP * (float)ti;
    const float dd = -logf(xe);
    const float cutv = (dd < 5.0f) ? (0.5f * (__cosf(dd * 0.6283185307179586f) + 1.0f)) : 0.0f;

    float h1[64];
    {
        const float4* bp = (const float4*)b1;
        #pragma unroll
        for (int j4 = 0; j4 < 16; ++j4) {
            float4 b = bp[j4];
            h1[4*j4+0] = b.x; h1[4*j4+1] = b.y; h1[4*j4+2] = b.z; h1[4*j4+3] = b.w;
        }
    }
    #pragma unroll 2
    for (int k = 0; k < 128; ++k) {
        float mean = K_START + K_STEP * (float)k;
        float t = xe - mean;
        float rk = cutv * __expf(-K_BETA * t * t);
        const float4* wr = (const float4*)(W1 + (k << 6));
        #pragma unroll
        for (int j4 = 0; j4 < 16; ++j4) {
            float4 wv = wr[j4];
            h1[4*j4+0] = fmaf(rk, wv.x, h1[4*j4+0]);
            h1[4*j4+1] = fmaf(rk, wv.y, h1[4*j4+1]);
            h1[4*j4+2] = fmaf(rk, wv.z, h1[4*j4+2]);
            h1[4*j4+3] = fmaf(rk, wv.w, h1[4*j4+3]);
        }
    }

    float h2[64];
    {
        const float4* bp = (const float4*)b2;
        #pragma unroll
        for (int j4 = 0; j4 < 16; ++j4) {
            float4 b = bp[j4];
            h2[4*j4+0] = b.x; h2[4*j4+1] = b.y; h2[4*j4+2] = b.z; h2[4*j4+3] = b.w;
        }
    }
    #pragma unroll
    for (int ch = 0; ch < 4; ++ch) {
        #pragma unroll
        for (int j = 0; j < 16; ++j) hb[tid*17 + j] = silu_f(h1[ch*16 + j]);
        for (int k = 0; k < 16; ++k) {
            float hk = hb[tid*17 + k];
            const float4* wr = (const float4*)(W2 + ((ch*16 + k) << 6));
            #pragma unroll
            for (int j4 = 0; j4 < 16; ++j4) {
                float4 wv = wr[j4];
                h2[4*j4+0] = fmaf(hk, wv.x, h2[4*j4+0]);
                h2[4*j4+1] = fmaf(hk, wv.y, h2[4*j4+1]);
                h2[4*j4+2] = fmaf(hk, wv.z, h2[4*j4+2]);
                h2[4*j4+3] = fmaf(hk, wv.w, h2[4*j4+3]);
            }
        }
    }

    float rad[16];
    #pragma unroll
    for (int cc = 0; cc < 16; ++cc) rad[cc] = 0.0f;
    #pragma unroll
    for (int ch = 0; ch < 4; ++ch) {
        #pragma unroll
        for (int j = 0; j < 16; ++j) hb[tid*17 + j] = silu_f(h2[ch*16 + j]);
        for (int k = 0; k < 16; ++k) {
            float hk = hb[tid*17 + k];
            const float4* wr = (const float4*)(W3 + ((ch*16 + k) << 4));
            #pragma unroll
            for (int c4 = 0; c4 < 4; ++c4) {
                float4 wv = wr[c4];
                rad[4*c4+0] = fmaf(hk, wv.x, rad[4*c4+0]);
                rad[4*c4+1] = fmaf(hk, wv.y, rad[4*c4+1]);
                rad[4*c4+2] = fmaf(hk, wv.z, rad[4*c4+2]);
                rad[4*c4+3] = fmaf(hk, wv.w, rad[4*c4+3]);
            }
        }
    }

    float4* rp = (float4*)(table + (size_t)ti * 16);
    rp[0] = make_float4(rad[0],  rad[1],  rad[2],  rad[3]);
    rp[1] = make_float4(rad[4],  rad[5],  rad[6],  rad[7]);
    rp[2] = make_float4(rad[8],  rad[9],  rad[10], rad[11]);
    rp[3] = make_float4(rad[12], rad[13], rad[14], rad[15]);
}

// ---------------- phase 2: half-bin counting sort + register agg + head ----------------
// Round 13's proven shape (448 thr, ~51 KB LDS, 62% VALUBusy, 91 us) with the
// new chunk source: this half-block's region = 196 one-line chunks at 32 KB
// stride (12.5 KB total -> L1-resident after pass A; pass B hits L1). Dead
// edges -> (0,0,0,K_START) sentinel -> table[0]==0 -> exact zero. Aggregation:
// 8-lane group streams its node's sorted records from LDS, REGISTER accumulate.
__global__ void __launch_bounds__(448)
agg_head(const float* __restrict__ pos, const unsigned* __restrict__ bins,
         const int* __restrict__ of_cnt, const int* __restrict__ of_src,
         const int* __restrict__ of_dst,
         const float* __restrict__ table,
         const float* __restrict__ atom_table, const int* __restrict__ node_atom,
         const int* __restrict__ batch,
         const float* __restrict__ Wh1, const float* __restrict__ bh1,
         const float* __restrict__ Wh2, const float* __restrict__ bh2,
         float* __restrict__ out, float isd, float isn)
{
    __shared__ int    lcnt[HALF], soff[HALF], scur[HALF];
    __shared__ int    ccache[BIN_BLOCKS];          // 784 B
    __shared__ float4 sgeo[SCAP];                  // 18.4 KB
    __shared__ float  nf_s[7][8][144];             // 32.3 KB
    const int tid = threadIdx.x;
    const int b   = blockIdx.x >> 1;
    const int h   = blockIdx.x & 1;
    const int lbase = h * HALF;
    const int gbase = b * NPB + lbase;

    if (tid < HALF) lcnt[tid] = 0;
    if (tid < BIN_BLOCKS)                           // pulls each chunk line into L1/L2
        ccache[tid] = (int)(bins[((size_t)tid * NB + b) * CHW] >> 27);
    __syncthreads();

    int ofn = *of_cnt; ofn = ofn < OFCAP ? ofn : OFCAP;   // ~300

    // ---- pass A: count this half's records ----
    const int TOT = BIN_BLOCKS * CHW;              // 3136 words
    for (int s = tid; s < TOT; s += 448) {
        int seg = s >> 4, k = s & 15;
        if (k < ccache[seg]) {
            unsigned rec = bins[((size_t)seg * NB + b) * CHW + k] & RECMASK;
            int l = (int)(rec & 127u) - lbase;
            if (l >= 0 && l < HALF) atomicAdd(&lcnt[l], 1);
        }
    }
    for (int i = tid; i < ofn; i += 448) {
        int l = of_dst[i] - gbase;
        if (l >= 0 && l < HALF) atomicAdd(&lcnt[l], 1);
    }
    __syncthreads();

    // ---- exclusive scan over 49 counters (wave 0) ----
    if (tid < 64) {
        int v = (tid < HALF) ? lcnt[tid] : 0;
        int x = v;
        #pragma unroll
        for (int off = 1; off < 64; off <<= 1) {
            int u = __shfl_up(x, off);
            if (tid >= off) x += u;
        }
        if (tid < HALF) { soff[tid] = x - v; scur[tid] = x - v; }
    }
    __syncthreads();

    // ---- pass B: geometry + scatter into sorted LDS (chunks now L1-hot) ----
    for (int s = tid; s < TOT; s += 448) {
        int seg = s >> 4, k = s & 15;
        if (k >= ccache[seg]) continue;
        unsigned rec = bins[((size_t)seg * NB + b) * CHW + k] & RECMASK;
        int local = (int)(rec & 127u);
        int l = local - lbase;
        if (l < 0 || l >= HALF) continue;
        int src = (int)(rec >> 7);
        int dst = b * NPB + local;
        float vx = pos[3*src+0] - pos[3*dst+0];
        float vy = pos[3*src+1] - pos[3*dst+1];
        float vz = pos[3*src+2] - pos[3*dst+2];
        float d2 = vx*vx + vy*vy + vz*vz;
        float4 g;
        if (d2 < 25.0f) {
            float ddv = sqrtf(d2);
            float inv = 1.0f / fmaxf(ddv, 1e-12f);
            g = make_float4(vx*inv, vy*inv, vz*inv, __expf(-ddv));
        } else {
            g = make_float4(0.0f, 0.0f, 0.0f, K_START);   // exact-zero sentinel
        }
        int p = atomicAdd(&scur[l], 1);
        if (p < SCAP) sgeo[p] = g;
    }
    for (int i = tid; i < ofn; i += 448) {
        int dst = of_dst[i];
        int l = dst - gbase;
        if (l < 0 || l >= HALF) continue;
        int src = of_src[i];
        float vx = pos[3*src+0] - pos[3*dst+0];
        float vy = pos[3*src+1] - pos[3*dst+1];
        float vz = pos[3*src+2] - pos[3*dst+2];
        float d2 = vx*vx + vy*vy + vz*vz;
        float4 g;
        if (d2 < 25.0f) {
            float ddv = sqrtf(d2);
            float inv = 1.0f / fmaxf(ddv, 1e-12f);
            g = make_float4(vx*inv, vy*inv, vz*inv, __expf(-ddv));
        } else {
            g = make_float4(0.0f, 0.0f, 0.0f, K_START);
        }
        int p = atomicAdd(&scur[l], 1);
        if (p < SCAP) sgeo[p] = g;
    }
    __syncthreads();

    // ---- aggregation: wave w, group g -> node slot l = w*8+g ----
    const int lane = tid & 63;
    const int w    = tid >> 6;           // 0..6
    const int g    = lane >> 3;
    const int c    = lane & 7;           // channels c and c+8
    const int l    = w * 8 + g;          // valid < HALF
    const int gn   = gbase + l;
    const bool valid = (l < HALF) && (gn < NND);

    float acc0[9], acc1[9];
    #pragma unroll
    for (int s = 0; s < 9; ++s) { acc0[s] = 0.0f; acc1[s] = 0.0f; }

    int start = 0, end = 0;
    if (valid) {
        start = soff[l];
        end   = start + lcnt[l];
        end   = end < SCAP ? end : SCAP;
    }

    for (int p = start; p < end; ++p) {
        float4 gv = sgeo[p];             // all 8 group lanes same addr -> broadcast
        float ux = gv.x, uy = gv.y, uz = gv.z, xe = gv.w;

        float t = (xe - K_START) * K_INVT;
        int i0 = (int)t;
        i0 = i0 < 0 ? 0 : (i0 > NT-2 ? NT-2 : i0);
        float fr = t - (float)i0;
        const float* tb = table + (size_t)i0 * 16 + c;
        float r0a = tb[0], r1a = tb[16];
        float r0b = tb[8], r1b = tb[24];
        float ra = fmaf(fr, r1a - r0a, r0a);
        float rb = fmaf(fr, r1b - r0b, r0b);

        float sh1 = 1.7320508075688772f * ux;
        float sh2 = 1.7320508075688772f * uy;
        float sh3 = 1.7320508075688772f * uz;
        float sh4 = 3.872983346207417f * ux * uz;
        float sh5 = 3.872983346207417f * ux * uy;
        float sh6 = 2.23606797749979f * (uy*uy - 0.5f*(ux*ux + uz*uz));
        float sh7 = 3.872983346207417f * uy * uz;
        float sh8 = 1.9364916731037085f * (uz*uz - ux*ux);

        acc0[0] += ra;                    acc1[0] += rb;
        acc0[1] = fmaf(ra, sh1, acc0[1]); acc1[1] = fmaf(rb, sh1, acc1[1]);
        acc0[2] = fmaf(ra, sh2, acc0[2]); acc1[2] = fmaf(rb, sh2, acc1[2]);
        acc0[3] = fmaf(ra, sh3, acc0[3]); acc1[3] = fmaf(rb, sh3, acc1[3]);
        acc0[4] = fmaf(ra, sh4, acc0[4]); acc1[4] = fmaf(rb, sh4, acc1[4]);
        acc0[5] = fmaf(ra, sh5, acc0[5]); acc1[5] = fmaf(rb, sh5, acc1[5]);
        acc0[6] = fmaf(ra, sh6, acc0[6]); acc1[6] = fmaf(rb, sh6, acc1[6]);
        acc0[7] = fmaf(ra, sh7, acc0[7]); acc1[7] = fmaf(rb, sh7, acc1[7]);
        acc0[8] = fmaf(ra, sh8, acc0[8]); acc1[8] = fmaf(rb, sh8, acc1[8]);
    }

    // nf = atom_table[atom] + deg_embed * isd -> this wave's LDS slab
    {
        int a = valid ? node_atom[gn] : 0;
        const float* at = atom_table + (size_t)a * 144;
        #pragma unroll
        for (int s = 0; s < 9; ++s) {
            nf_s[w][g][c*9 + s]     = fmaf(acc0[s], isd, at[c*9 + s]);
            nf_s[w][g][(c+8)*9 + s] = fmaf(acc1[s], isd, at[(c+8)*9 + s]);
        }
    }
    // same-wave LDS write->read: hardware-ordered, no barrier

    // ---- head: hn = silu(nf @ Wh1 + bh1); energy = hn @ Wh2 + bh2 ----
    float A0[8], A1[8], A2[8];
    {
        float bb0 = bh1[lane], bb1 = bh1[lane + 64];
        float bb2 = (lane < 16) ? bh1[lane + 128] : 0.0f;
        #pragma unroll
        for (int q = 0; q < 8; ++q) { A0[q] = bb0; A1[q] = bb1; A2[q] = bb2; }
    }

    for (int k4 = 0; k4 < 36; ++k4) {
        float4 nq[8];
        #pragma unroll
        for (int q = 0; q < 8; ++q)
            nq[q] = *(const float4*)&nf_s[w][q][k4*4];      // LDS broadcast
        const float* wrow = Wh1 + (size_t)(k4*4) * 144;     // L2-hot global
#define HSTEP(COMP, OFF) { \
        float w0 = wrow[(OFF)*144 + lane]; \
        float w1 = wrow[(OFF)*144 + lane + 64]; \
        float w2 = (lane < 16) ? wrow[(OFF)*144 + lane + 128] : 0.0f; \
        _Pragma("unroll") \
        for (int q = 0; q < 8; ++q) { \
            float nk = nq[q].COMP; \
            A0[q] = fmaf(nk, w0, A0[q]); \
            A1[q] = fmaf(nk, w1, A1[q]); \
            A2[q] = fmaf(nk, w2, A2[q]); } }
        HSTEP(x, 0) HSTEP(y, 1) HSTEP(z, 2) HSTEP(w, 3)
#undef HSTEP
    }

    float wl0 = Wh2[lane], wl1 = Wh2[lane + 64];
    float wl2 = (lane < 16) ? Wh2[lane + 128] : 0.0f;
    float bv  = bh2[0];
    #pragma unroll
    for (int q = 0; q < 8; ++q) {
        float en = silu_f(A0[q]) * wl0 + silu_f(A1[q]) * wl1;
        if (lane < 16) en = fmaf(silu_f(A2[q]), wl2, en);
        en += __shfl_down(en, 32);
        en += __shfl_down(en, 16);
        en += __shfl_down(en, 8);
        en += __shfl_down(en, 4);
        en += __shfl_down(en, 2);
        en += __shfl_down(en, 1);
        int lq = w * 8 + q;
        int gq = gbase + lq;
        if (lane == 0 && lq < HALF && gq < NND) {
            unsafeAtomicAdd(out + batch[gq], (en + bv) * isn);
        }
    }
}

extern "C" void kernel_launch(void* const* d_in, const int* in_sizes, int n_in,
                              void* d_out, int out_size, void* d_ws, size_t ws_size,
                              hipStream_t stream) {
    const float* pos        = (const float*)d_in[0];
    const float* atom_table = (const float*)d_in[1];
    const float* W1         = (const float*)d_in[2];
    const float* b1         = (const float*)d_in[3];
    const float* W2         = (const float*)d_in[4];
    const float* b2         = (const float*)d_in[5];
    const float* W3         = (const float*)d_in[6];
    const float* Wh1        = (const float*)d_in[7];
    const float* bh1        = (const float*)d_in[8];
    const float* Wh2        = (const float*)d_in[9];
    const float* bh2        = (const float*)d_in[10];
    const int*   node_atom  = (const int*)d_in[11];
    const int*   edge_src   = (const int*)d_in[12];
    const int*   edge_dst   = (const int*)d_in[13];
    const int*   batch      = (const int*)d_in[14];

    float* out = (float*)d_out;

    // workspace layout (16B-aligned where needed)
    char*     wsb    = (char*)d_ws;
    int*      of_cnt = (int*)(wsb);                  // [1] + pad        64 B
    int*      of_src = (int*)(wsb + 64);             // [OFCAP]          32768 B
    int*      of_dst = (int*)(wsb + 32832);          // [OFCAP]          32768 B
    float*    table  = (float*)(wsb + 65600);        // [NT][16]         65536 B (16B-al)
    unsigned* bins   = (unsigned*)(wsb + 131136);    // [196][512][16]   6.42 MB (16B-al)

    hipMemsetAsync(of_cnt, 0, 4, stream);

    bin_table<<<BIN_BLOCKS + TBL_BLOCKS, 1024, 0, stream>>>(
        edge_src, edge_dst, bins, of_cnt, of_src, of_dst,
        W1, b1, W2, b2, W3, table, out);

    float isd = 1.0f / sqrtf(15.57930850982666f);
    float isn = 1.0f / sqrtf(18.03065905448718f);
    agg_head<<<NB * 2, 448, 0, stream>>>(
        pos, bins, of_cnt, of_src, of_dst, table, atom_table, node_atom,
        batch, Wh1, bh1, Wh2, bh2, out, isd, isn);
}

// Round 17
// 197.016 us; speedup vs baseline: 1.3864x; 1.2299x over previous
//
#include <hip/hip_runtime.h>
#include <math.h>

#define NND 50000
#define NED 800000
#define NGR 2048
#define NT  1024          // rad-table entries (uniform in xe = exp(-d))
#define NB  512           // bins of NPB nodes
#define NPB 98
#define HALF 49           // nodes per agg block (half-bin, round-13 proven shape)
#define EPB 4096          // edges per bin block
#define BIN_BLOCKS 196    // 196*4096 = 802816 >= NED
#define TBL_BLOCKS 64     // 64 blocks x 16 waves = 1024 waves = one per table entry
#define CHW 16            // chunk = 16 words = exactly one 64 B line
#define LCAP 16           // slots 0..15; count packed in bits 27..31 of slot 0
#define LSTR 17           // LDS record row stride (odd -> banks spread)
#define SCAP 1152         // sorted-geo LDS capacity per half-bin (mean 784, +13 sigma)
#define OFCAP 8192        // global overflow capacity (expected usage ~300)
#define RECMASK 0x07FFFFFFu

// exp(-5) and derived RBF constants, computed in double then rounded once.
constexpr double dSTART = 0.006737946999085467;
constexpr float  K_START = (float)dSTART;
constexpr float  K_STEP  = (float)((1.0 - dSTART) / 127.0);
constexpr float  K_BETA  = (float)(1.0 / ((2.0/128.0*(1.0-dSTART)) * (2.0/128.0*(1.0-dSTART))));
constexpr float  K_TSTEP = (float)((1.0 - dSTART) / (double)(NT - 1));
constexpr float  K_INVT  = (float)((double)(NT - 1) / (1.0 - dSTART));

__device__ __forceinline__ float silu_f(float x) {
    return x * __builtin_amdgcn_rcpf(1.0f + __expf(-x));
}

// ---------------- phase 1: LDS-multisplit binning || WAVE-PARALLEL rad-table ----------------
// Bin blocks (unchanged from round 16): dense lcnt (banks spread), lbuf stride 17,
// NO global atomics, contiguous 32 KB dump; overflow -> tiny global list.
// Table path REBUILT: rounds 10-16 ran 1 thread = 1 entry (26-KFLOP serial MLP,
// 1 wave/SIMD, every weight-load latency exposed -> the hidden ~90 us tail at
// 1% VALUBusy). Now 1 WAVE = 1 entry: lane j owns channel j, k-loop serial with
// COALESCED W-row loads; silu'd activations broadcast via per-wave LDS buffer.
// Same per-channel accumulation order -> bit-identical table.
__global__ void __launch_bounds__(1024)
bin_table(const int* __restrict__ esrc, const int* __restrict__ edst,
          unsigned* __restrict__ bins,
          int* __restrict__ of_cnt, int* __restrict__ of_src, int* __restrict__ of_dst,
          const float* __restrict__ W1, const float* __restrict__ b1,
          const float* __restrict__ W2, const float* __restrict__ b2,
          const float* __restrict__ W3, float* __restrict__ table,
          float* __restrict__ out)
{
    __shared__ int      lcnt[NB];                // dense: bank = b%32
    __shared__ unsigned lbuf[NB * LSTR];         // 34.8 KB; table path aliases 4.3 KB
    const int bid = blockIdx.x;
    const int tid = threadIdx.x;

    if (bid < BIN_BLOCKS) {
        if (tid < NB) lcnt[tid] = 0;
        __syncthreads();
        const int e0 = bid * EPB;
        #pragma unroll
        for (int r = 0; r < 4; ++r) {
            int e = e0 + r * 1024 + tid;
            if (e < NED) {
                int dst = edst[e];
                int src = esrc[e];
                int b = dst / NPB;                   // const divide -> magic mul
                unsigned rec = ((unsigned)src << 7) | (unsigned)(dst - b * NPB);
                int p = atomicAdd(&lcnt[b], 1);
                if (p < LCAP) lbuf[b * LSTR + p] = rec;
                else {                               // ~300 edges total
                    int gp = atomicAdd(of_cnt, 1);
                    if (gp < OFCAP) { of_src[gp] = src; of_dst[gp] = dst; }
                }
            }
        }
        __syncthreads();
        // contiguous dump: this block owns bins[bid][*][*] = 32 KB stream
        unsigned* dp = bins + (size_t)bid * NB * CHW;
        for (int i = tid; i < NB * CHW; i += 1024) {
            int b = i >> 4, k = i & 15;
            int c = lcnt[b]; c = c < LCAP ? c : LCAP;
            unsigned val;
            if (k == 0) val = ((c > 0) ? lbuf[b * LSTR] : 0u) | ((unsigned)c << 27);
            else        val = lbuf[b * LSTR + k];    // garbage beyond c: reader-guarded
            dp[i] = val;
        }
        return;
    }

    // ---- table path: one WAVE per entry; 64 blocks x 16 waves = 1024 entries ----
    const int tb   = bid - BIN_BLOCKS;               // 0..63
    const int lane = tid & 63;
    const int w    = tid >> 6;                       // 0..15
    const int ti   = tb * 16 + w;                    // entry id 0..1023
    float* hl = (float*)lbuf + w * 68;               // per-wave 64-float buffer (+4 pad)

    if (tb < 2) out[tb * 1024 + tid] = 0.0f;         // zero out[2048]

    const float xe = K_START + K_TSTEP * (float)ti;
    const float dd = -logf(xe);
    const float cutv = (dd < 5.0f) ? (0.5f * (__cosf(dd * 0.6283185307179586f) + 1.0f)) : 0.0f;

    // layer 1: lane j accumulates h1_j over k (coalesced W1 row loads)
    float h1 = b1[lane];
    #pragma unroll 4
    for (int k = 0; k < 128; ++k) {
        float mean = K_START + K_STEP * (float)k;
        float t = xe - mean;
        float rk = cutv * __expf(-K_BETA * t * t);
        h1 = fmaf(rk, W1[(k << 6) + lane], h1);
    }
    hl[lane] = silu_f(h1);
    // same-wave LDS write->read: hardware-ordered, no barrier

    // layer 2: lane j accumulates h2_j; hl[k] is an LDS broadcast read
    float h2 = b2[lane];
    #pragma unroll 4
    for (int k = 0; k < 64; ++k)
        h2 = fmaf(hl[k], W2[(k << 6) + lane], h2);
    float s2 = silu_f(h2);                           // read hl done before overwrite
    hl[lane] = s2;

    // layer 3: lanes 0..15 own the 16 radial channels
    if (lane < 16) {
        float rad = 0.0f;
        #pragma unroll 4
        for (int k = 0; k < 64; ++k)
            rad = fmaf(hl[k], W3[(k << 4) + lane], rad);
        table[ti * 16 + lane] = rad;                 // 64 B coalesced per wave
    }
}

// ---------------- phase 2: half-bin counting sort + register agg + head ----------------
// Unchanged from round 16 (98 us, 62% VALUBusy).
__global__ void __launch_bounds__(448)
agg_head(const float* __restrict__ pos, const unsigned* __restrict__ bins,
         const int* __restrict__ of_cnt, const int* __restrict__ of_src,
         const int* __restrict__ of_dst,
         const float* __restrict__ table,
         const float* __restrict__ atom_table, const int* __restrict__ node_atom,
         const int* __restrict__ batch,
         const float* __restrict__ Wh1, const float* __restrict__ bh1,
         const float* __restrict__ Wh2, const float* __restrict__ bh2,
         float* __restrict__ out, float isd, float isn)
{
    __shared__ int    lcnt[HALF], soff[HALF], scur[HALF];
    __shared__ int    ccache[BIN_BLOCKS];          // 784 B
    __shared__ float4 sgeo[SCAP];                  // 18.4 KB
    __shared__ float  nf_s[7][8][144];             // 32.3 KB
    const int tid = threadIdx.x;
    const int b   = blockIdx.x >> 1;
    const int h   = blockIdx.x & 1;
    const int lbase = h * HALF;
    const int gbase = b * NPB + lbase;

    if (tid < HALF) lcnt[tid] = 0;
    if (tid < BIN_BLOCKS)                           // pulls each chunk line into L1/L2
        ccache[tid] = (int)(bins[((size_t)tid * NB + b) * CHW] >> 27);
    __syncthreads();

    int ofn = *of_cnt; ofn = ofn < OFCAP ? ofn : OFCAP;   // ~300

    // ---- pass A: count this half's records ----
    const int TOT = BIN_BLOCKS * CHW;              // 3136 words
    for (int s = tid; s < TOT; s += 448) {
        int seg = s >> 4, k = s & 15;
        if (k < ccache[seg]) {
            unsigned rec = bins[((size_t)seg * NB + b) * CHW + k] & RECMASK;
            int l = (int)(rec & 127u) - lbase;
            if (l >= 0 && l < HALF) atomicAdd(&lcnt[l], 1);
        }
    }
    for (int i = tid; i < ofn; i += 448) {
        int l = of_dst[i] - gbase;
        if (l >= 0 && l < HALF) atomicAdd(&lcnt[l], 1);
    }
    __syncthreads();

    // ---- exclusive scan over 49 counters (wave 0) ----
    if (tid < 64) {
        int v = (tid < HALF) ? lcnt[tid] : 0;
        int x = v;
        #pragma unroll
        for (int off = 1; off < 64; off <<= 1) {
            int u = __shfl_up(x, off);
            if (tid >= off) x += u;
        }
        if (tid < HALF) { soff[tid] = x - v; scur[tid] = x - v; }
    }
    __syncthreads();

    // ---- pass B: geometry + scatter into sorted LDS (chunks L1-hot) ----
    for (int s = tid; s < TOT; s += 448) {
        int seg = s >> 4, k = s & 15;
        if (k >= ccache[seg]) continue;
        unsigned rec = bins[((size_t)seg * NB + b) * CHW + k] & RECMASK;
        int local = (int)(rec & 127u);
        int l = local - lbase;
        if (l < 0 || l >= HALF) continue;
        int src = (int)(rec >> 7);
        int dst = b * NPB + local;
        float vx = pos[3*src+0] - pos[3*dst+0];
        float vy = pos[3*src+1] - pos[3*dst+1];
        float vz = pos[3*src+2] - pos[3*dst+2];
        float d2 = vx*vx + vy*vy + vz*vz;
        float4 g;
        if (d2 < 25.0f) {
            float ddv = sqrtf(d2);
            float inv = 1.0f / fmaxf(ddv, 1e-12f);
            g = make_float4(vx*inv, vy*inv, vz*inv, __expf(-ddv));
        } else {
            g = make_float4(0.0f, 0.0f, 0.0f, K_START);   // exact-zero sentinel
        }
        int p = atomicAdd(&scur[l], 1);
        if (p < SCAP) sgeo[p] = g;
    }
    for (int i = tid; i < ofn; i += 448) {
        int dst = of_dst[i];
        int l = dst - gbase;
        if (l < 0 || l >= HALF) continue;
        int src = of_src[i];
        float vx = pos[3*src+0] - pos[3*dst+0];
        float vy = pos[3*src+1] - pos[3*dst+1];
        float vz = pos[3*src+2] - pos[3*dst+2];
        float d2 = vx*vx + vy*vy + vz*vz;
        float4 g;
        if (d2 < 25.0f) {
            float ddv = sqrtf(d2);
            float inv = 1.0f / fmaxf(ddv, 1e-12f);
            g = make_float4(vx*inv, vy*inv, vz*inv, __expf(-ddv));
        } else {
            g = make_float4(0.0f, 0.0f, 0.0f, K_START);
        }
        int p = atomicAdd(&scur[l], 1);
        if (p < SCAP) sgeo[p] = g;
    }
    __syncthreads();

    // ---- aggregation: wave w, group g -> node slot l = w*8+g ----
    const int lane = tid & 63;
    const int w    = tid >> 6;           // 0..6
    const int g    = lane >> 3;
    const int c    = lane & 7;           // channels c and c+8
    const int l    = w * 8 + g;          // valid < HALF
    const int gn   = gbase + l;
    const bool valid = (l < HALF) && (gn < NND);

    float acc0[9], acc1[9];
    #pragma unroll
    for (int s = 0; s < 9; ++s) { acc0[s] = 0.0f; acc1[s] = 0.0f; }

    int start = 0, end = 0;
    if (valid) {
        start = soff[l];
        end   = start + lcnt[l];
        end   = end < SCAP ? end : SCAP;
    }

    for (int p = start; p < end; ++p) {
        float4 gv = sgeo[p];             // all 8 group lanes same addr -> broadcast
        float ux = gv.x, uy = gv.y, uz = gv.z, xe = gv.w;

        float t = (xe - K_START) * K_INVT;
        int i0 = (int)t;
        i0 = i0 < 0 ? 0 : (i0 > NT-2 ? NT-2 : i0);
        float fr = t - (float)i0;
        const float* tb = table + (size_t)i0 * 16 + c;
        float r0a = tb[0], r1a = tb[16];
        float r0b = tb[8], r1b = tb[24];
        float ra = fmaf(fr, r1a - r0a, r0a);
        float rb = fmaf(fr, r1b - r0b, r0b);

        float sh1 = 1.7320508075688772f * ux;
        float sh2 = 1.7320508075688772f * uy;
        float sh3 = 1.7320508075688772f * uz;
        float sh4 = 3.872983346207417f * ux * uz;
        float sh5 = 3.872983346207417f * ux * uy;
        float sh6 = 2.23606797749979f * (uy*uy - 0.5f*(ux*ux + uz*uz));
        float sh7 = 3.872983346207417f * uy * uz;
        float sh8 = 1.9364916731037085f * (uz*uz - ux*ux);

        acc0[0] += ra;                    acc1[0] += rb;
        acc0[1] = fmaf(ra, sh1, acc0[1]); acc1[1] = fmaf(rb, sh1, acc1[1]);
        acc0[2] = fmaf(ra, sh2, acc0[2]); acc1[2] = fmaf(rb, sh2, acc1[2]);
        acc0[3] = fmaf(ra, sh3, acc0[3]); acc1[3] = fmaf(rb, sh3, acc1[3]);
        acc0[4] = fmaf(ra, sh4, acc0[4]); acc1[4] = fmaf(rb, sh4, acc1[4]);
        acc0[5] = fmaf(ra, sh5, acc0[5]); acc1[5] = fmaf(rb, sh5, acc1[5]);
        acc0[6] = fmaf(ra, sh6, acc0[6]); acc1[6] = fmaf(rb, sh6, acc1[6]);
        acc0[7] = fmaf(ra, sh7, acc0[7]); acc1[7] = fmaf(rb, sh7, acc1[7]);
        acc0[8] = fmaf(ra, sh8, acc0[8]); acc1[8] = fmaf(rb, sh8, acc1[8]);
    }

    // nf = atom_table[atom] + deg_embed * isd -> this wave's LDS slab
    {
        int a = valid ? node_atom[gn] : 0;
        const float* at = atom_table + (size_t)a * 144;
        #pragma unroll
        for (int s = 0; s < 9; ++s) {
            nf_s[w][g][c*9 + s]     = fmaf(acc0[s], isd, at[c*9 + s]);
            nf_s[w][g][(c+8)*9 + s] = fmaf(acc1[s], isd, at[(c+8)*9 + s]);
        }
    }
    // same-wave LDS write->read: hardware-ordered, no barrier

    // ---- head: hn = silu(nf @ Wh1 + bh1); energy = hn @ Wh2 + bh2 ----
    float A0[8], A1[8], A2[8];
    {
        float bb0 = bh1[lane], bb1 = bh1[lane + 64];
        float bb2 = (lane < 16) ? bh1[lane + 128] : 0.0f;
        #pragma unroll
        for (int q = 0; q < 8; ++q) { A0[q] = bb0; A1[q] = bb1; A2[q] = bb2; }
    }

    for (int k4 = 0; k4 < 36; ++k4) {
        float4 nq[8];
        #pragma unroll
        for (int q = 0; q < 8; ++q)
            nq[q] = *(const float4*)&nf_s[w][q][k4*4];      // LDS broadcast
        const float* wrow = Wh1 + (size_t)(k4*4) * 144;     // L2-hot global
#define HSTEP(COMP, OFF) { \
        float w0 = wrow[(OFF)*144 + lane]; \
        float w1 = wrow[(OFF)*144 + lane + 64]; \
        float w2 = (lane < 16) ? wrow[(OFF)*144 + lane + 128] : 0.0f; \
        _Pragma("unroll") \
        for (int q = 0; q < 8; ++q) { \
            float nk = nq[q].COMP; \
            A0[q] = fmaf(nk, w0, A0[q]); \
            A1[q] = fmaf(nk, w1, A1[q]); \
            A2[q] = fmaf(nk, w2, A2[q]); } }
        HSTEP(x, 0) HSTEP(y, 1) HSTEP(z, 2) HSTEP(w, 3)
#undef HSTEP
    }

    float wl0 = Wh2[lane], wl1 = Wh2[lane + 64];
    float wl2 = (lane < 16) ? Wh2[lane + 128] : 0.0f;
    float bv  = bh2[0];
    #pragma unroll
    for (int q = 0; q < 8; ++q) {
        float en = silu_f(A0[q]) * wl0 + silu_f(A1[q]) * wl1;
        if (lane < 16) en = fmaf(silu_f(A2[q]), wl2, en);
        en += __shfl_down(en, 32);
        en += __shfl_down(en, 16);
        en += __shfl_down(en, 8);
        en += __shfl_down(en, 4);
        en += __shfl_down(en, 2);
        en += __shfl_down(en, 1);
        int lq = w * 8 + q;
        int gq = gbase + lq;
        if (lane == 0 && lq < HALF && gq < NND) {
            unsafeAtomicAdd(out + batch[gq], (en + bv) * isn);
        }
    }
}

extern "C" void kernel_launch(void* const* d_in, const int* in_sizes, int n_in,
                              void* d_out, int out_size, void* d_ws, size_t ws_size,
                              hipStream_t stream) {
    const float* pos        = (const float*)d_in[0];
    const float* atom_table = (const float*)d_in[1];
    const float* W1         = (const float*)d_in[2];
    const float* b1         = (const float*)d_in[3];
    const float* W2         = (const float*)d_in[4];
    const float* b2         = (const float*)d_in[5];
    const float* W3         = (const float*)d_in[6];
    const float* Wh1        = (const float*)d_in[7];
    const float* bh1        = (const float*)d_in[8];
    const float* Wh2        = (const float*)d_in[9];
    const float* bh2        = (const float*)d_in[10];
    const int*   node_atom  = (const int*)d_in[11];
    const int*   edge_src   = (const int*)d_in[12];
    const int*   edge_dst   = (const int*)d_in[13];
    const int*   batch      = (const int*)d_in[14];

    float* out = (float*)d_out;

    // workspace layout (16B-aligned where needed)
    char*     wsb    = (char*)d_ws;
    int*      of_cnt = (int*)(wsb);                  // [1] + pad        64 B
    int*      of_src = (int*)(wsb + 64);             // [OFCAP]          32768 B
    int*      of_dst = (int*)(wsb + 32832);          // [OFCAP]          32768 B
    float*    table  = (float*)(wsb + 65600);        // [NT][16]         65536 B (16B-al)
    unsigned* bins   = (unsigned*)(wsb + 131136);    // [196][512][16]   6.42 MB (16B-al)

    hipMemsetAsync(of_cnt, 0, 4, stream);

    bin_table<<<BIN_BLOCKS + TBL_BLOCKS, 1024, 0, stream>>>(
        edge_src, edge_dst, bins, of_cnt, of_src, of_dst,
        W1, b1, W2, b2, W3, table, out);

    float isd = 1.0f / sqrtf(15.57930850982666f);
    float isn = 1.0f / sqrtf(18.03065905448718f);
    agg_head<<<NB * 2, 448, 0, stream>>>(
        pos, bins, of_cnt, of_src, of_dst, table, atom_table, node_atom,
        batch, Wh1, bh1, Wh2, bh2, out, isd, isn);
}